// Round 1
// baseline (641.009 us; speedup 1.0000x reference)
//
#include <hip/hip_runtime.h>

// ImplicitMLP: GFF(2->256 via sin/cos) -> LR(256->256, r70) -> LR(256->128, r10)
//              -> 128->32 -> 32->16 -> 16->3. Fully fused, 1 thread = 1 pixel.
// Low-rank factorization applied directly: x@(L@R)^T == (x@R^T)@L^T.
//
// Workspace layout (floats):
//   R1T  [256][70]  : R1T[m][r] = R1[r][m]        (R1 is (70,256))
//   R2T  [256][10]  : R2T[j][t] = R2[t][j]        (R2 is (10,256))
//   W3T  [128][32]  : W3T[i][q] = W3[q][i]        (W3 is (32,128))
//   W4T  [ 32][16]  : W4T[q][p] = W4[p][q]        (W4 is (16,32))

#define R1T_OFF 0
#define R2T_OFF 17920
#define W3T_OFF (17920 + 2560)
#define W4T_OFF (17920 + 2560 + 4096)
#define WS_TOTAL (17920 + 2560 + 4096 + 512)   // 25088 floats = 100352 B

__global__ __launch_bounds__(256) void prep_transpose(
    const float* __restrict__ R1, const float* __restrict__ R2,
    const float* __restrict__ W3, const float* __restrict__ W4,
    float* __restrict__ ws) {
  int e = blockIdx.x * 256 + threadIdx.x;
  if (e < 17920) {                       // R1T[m][r] = R1[r*256 + m]
    int m = e / 70, r = e - m * 70;
    ws[R1T_OFF + e] = R1[r * 256 + m];
  } else if (e < 20480) {                // R2T[j][t] = R2[t*256 + j]
    int f = e - 17920;
    int j = f / 10, t = f - j * 10;
    ws[R2T_OFF + f] = R2[t * 256 + j];
  } else if (e < 24576) {                // W3T[i][q] = W3[q*128 + i]
    int f = e - 20480;
    int i = f >> 5, q = f & 31;
    ws[W3T_OFF + f] = W3[q * 128 + i];
  } else if (e < 25088) {                // W4T[q][p] = W4[p*32 + q]
    int f = e - 24576;
    int q = f >> 4, p = f & 15;
    ws[W4T_OFF + f] = W4[p * 32 + q];
  }
}

__global__ __launch_bounds__(256, 2) void implicit_mlp_fused(
    const float* __restrict__ coords,  // (128, 2, 64, 64)
    const float* __restrict__ Bmat,    // (2, 128)
    const float* __restrict__ L1,      // (256, 70)
    const float* __restrict__ b1,      // (256)
    const float* __restrict__ L2,      // (128, 10)
    const float* __restrict__ b2,      // (128)
    const float* __restrict__ b3v,     // (32)
    const float* __restrict__ b4v,     // (16)
    const float* __restrict__ W5,      // (3, 16)
    const float* __restrict__ b5,      // (3)
    const float* __restrict__ ws,      // transposed weights (read-only here)
    float* __restrict__ out) {         // (1, 524288, 3) fp32
  const float* __restrict__ R1T = ws + R1T_OFF;
  const float* __restrict__ R2T = ws + R2T_OFF;
  const float* __restrict__ W3T = ws + W3T_OFF;
  const float* __restrict__ W4T = ws + W4T_OFF;

  int g = blockIdx.x * 256 + threadIdx.x;      // global pixel id, 0..524287
  int b = g >> 12;                             // batch
  int hw = g & 4095;                           // h*64 + w
  float c0 = coords[b * 8192 + hw];
  float c1 = coords[b * 8192 + 4096 + hw];

  // ---- Phase A: GFF + y = x @ R1^T  (y[r] = sum_m s_m*R1[r][m] + c_m*R1[r][m+128])
  float y[70];
#pragma unroll
  for (int r = 0; r < 70; ++r) y[r] = 0.0f;

  for (int m = 0; m < 128; ++m) {
    // proj = 2*pi*u; v_sin_f32 takes revolutions: sin(2*pi*t). Reduce with fract.
    float u = fmaf(c0, Bmat[m], c1 * Bmat[128 + m]);
    float t = u - floorf(u);
    float s = __builtin_amdgcn_sinf(t);
    float c = __builtin_amdgcn_cosf(t);
    const float* __restrict__ wsin = R1T + m * 70;          // R1T row m
    const float* __restrict__ wcos = R1T + (m + 128) * 70;  // R1T row m+128
#pragma unroll
    for (int r = 0; r < 70; ++r)
      y[r] = fmaf(s, wsin[r], fmaf(c, wcos[r], y[r]));
  }

  // ---- Phase B: a1 = relu(y @ L1^T + b1), streamed into z = a1 @ R2^T
  float z[10];
#pragma unroll
  for (int t = 0; t < 10; ++t) z[t] = 0.0f;

  for (int j = 0; j < 256; ++j) {
    float d = b1[j];
    const float* __restrict__ lw = L1 + j * 70;   // L1 row j (contiguous)
#pragma unroll
    for (int r = 0; r < 70; ++r) d = fmaf(y[r], lw[r], d);
    d = fmaxf(d, 0.0f);
    const float* __restrict__ rw = R2T + j * 10;
#pragma unroll
    for (int t = 0; t < 10; ++t) z[t] = fmaf(d, rw[t], z[t]);
  }

  // ---- Phase C: a2 = relu(z @ L2^T + b2), streamed into o3 = a2 @ W3^T + b3
  float o3[32];
#pragma unroll
  for (int q = 0; q < 32; ++q) o3[q] = b3v[q];

  for (int i = 0; i < 128; ++i) {
    float d = b2[i];
    const float* __restrict__ lw = L2 + i * 10;   // L2 row i (contiguous)
#pragma unroll
    for (int t = 0; t < 10; ++t) d = fmaf(z[t], lw[t], d);
    d = fmaxf(d, 0.0f);
    const float* __restrict__ w3 = W3T + i * 32;
#pragma unroll
    for (int q = 0; q < 32; ++q) o3[q] = fmaf(d, w3[q], o3[q]);
  }

  // ---- Phase D: a3 = relu(o3), o4 = a3 @ W4^T + b4, then relu
  float o4[16];
#pragma unroll
  for (int p = 0; p < 16; ++p) o4[p] = b4v[p];
#pragma unroll
  for (int q = 0; q < 32; ++q) {
    float a = fmaxf(o3[q], 0.0f);
    const float* __restrict__ w4 = W4T + q * 16;
#pragma unroll
    for (int p = 0; p < 16; ++p) o4[p] = fmaf(a, w4[p], o4[p]);
  }
#pragma unroll
  for (int p = 0; p < 16; ++p) o4[p] = fmaxf(o4[p], 0.0f);

  // ---- Phase E: out = o4 @ W5^T + b5 (no relu)
#pragma unroll
  for (int e = 0; e < 3; ++e) {
    float acc = b5[e];
    const float* __restrict__ w5 = W5 + e * 16;
#pragma unroll
    for (int p = 0; p < 16; ++p) acc = fmaf(o4[p], w5[p], acc);
    out[g * 3 + e] = acc;
  }
}

extern "C" void kernel_launch(void* const* d_in, const int* in_sizes, int n_in,
                              void* d_out, int out_size, void* d_ws, size_t ws_size,
                              hipStream_t stream) {
  const float* coords = (const float*)d_in[0];
  const float* Bmat   = (const float*)d_in[1];
  const float* L1     = (const float*)d_in[2];
  const float* R1     = (const float*)d_in[3];
  const float* b1     = (const float*)d_in[4];
  const float* L2     = (const float*)d_in[5];
  const float* R2     = (const float*)d_in[6];
  const float* b2     = (const float*)d_in[7];
  const float* W3     = (const float*)d_in[8];
  const float* b3     = (const float*)d_in[9];
  const float* W4     = (const float*)d_in[10];
  const float* b4     = (const float*)d_in[11];
  const float* W5     = (const float*)d_in[12];
  const float* b5     = (const float*)d_in[13];
  float* ws  = (float*)d_ws;
  float* out = (float*)d_out;

  // transpose small weights into workspace (25088 elements)
  prep_transpose<<<98, 256, 0, stream>>>(R1, R2, W3, W4, ws);
  // fused MLP: 524288 pixels, 1 thread each
  implicit_mlp_fused<<<2048, 256, 0, stream>>>(coords, Bmat, L1, b1, L2, b2,
                                               b3, b4, W5, b5, ws, out);
}

// Round 2
// 342.362 us; speedup vs baseline: 1.8723x; 1.8723x over previous
//
#include <hip/hip_runtime.h>

// ImplicitMLP via MFMA (bf16 in / fp32 accum) for phases A, B1, B2; VALU fp32
// for the small CDE tail. 1 wave (64 threads) = 64 pixels per block.
//
// Phases:
//   A : y[64x80]   = X[64x256] @ R1T    (K=256, interleaved sin/cos k-order)
//   B1: a1[64x256] = relu(y[64x96] @ L1T + b1)    (K=96, y zero-padded)
//   B2: z[64x16]   = a1[64x256] @ R2T   (K=256, t>=10 zero)
//   CDE: per-lane fp32: relu(z@L2T+b2) -> W3 -> W4 -> W5 (6.3k MAC)
//
// Workspace (bytes):
//   R1p  @      0 : [kt8][n80][k32]  bf16 B-operand pack (feat = interleaved sin/cos)
//   L1p  @  40960 : [kt3][n256][k32] bf16 (k>=70 zero)
//   R2p  @  90112 : [kt8][n16][k32]  bf16 (n>=10 zero)
//   W3T  @  98304 : [i128][q32] f32
//   W4T  @ 114688 : [q32][p16]  f32      total 116736 B

typedef __attribute__((ext_vector_type(8))) short bf16x8;
typedef __attribute__((ext_vector_type(4))) float f32x4;
typedef __attribute__((ext_vector_type(4))) int i32x4;

__device__ inline unsigned short f2bf(float f) {
  unsigned u = __float_as_uint(f);
  return (unsigned short)((u + 0x7FFFu + ((u >> 16) & 1u)) >> 16);
}

__global__ __launch_bounds__(256) void prep_pack(
    const float* __restrict__ R1, const float* __restrict__ L1,
    const float* __restrict__ R2, const float* __restrict__ W3,
    const float* __restrict__ W4, void* __restrict__ ws) {
  unsigned short* w16 = (unsigned short*)ws;
  float* wf = (float*)ws;
  int e = blockIdx.x * 256 + threadIdx.x;
  if (e < 20480) {                      // R1p: B[k=feat][n=r], r<70 real
    int kt = e / 2560, rem = e % 2560;
    int n = rem >> 5, oj = rem & 31;
    int k = kt * 32 + oj;               // interleaved: even=sin(m), odd=cos(m)
    int feat = (k & 1) ? 128 + (k >> 1) : (k >> 1);
    float v = (n < 70) ? R1[n * 256 + feat] : 0.0f;  // R1 (70,256): R1[r][m]
    w16[e] = f2bf(v);
  } else if (e < 45056) {               // L1p: B[k=r][n=j], k<70 real
    int f = e - 20480;
    int kt = f / 8192, rem = f % 8192;
    int n = rem >> 5, oj = rem & 31;
    int k = kt * 32 + oj;
    float v = (k < 70) ? L1[n * 70 + k] : 0.0f;      // L1 (256,70): L1[j][r]
    w16[e] = f2bf(v);
  } else if (e < 49152) {               // R2p: B[k=j][n=t], n<10 real
    int g = e - 45056;
    int kt = g / 512, rem = g % 512;
    int n = rem >> 5, oj = rem & 31;
    int k = kt * 32 + oj;
    float v = (n < 10) ? R2[n * 256 + k] : 0.0f;     // R2 (10,256): R2[t][j]
    w16[e] = f2bf(v);
  } else if (e < 53248) {               // W3T[i][q] = W3[q][i], f32
    int h = e - 49152;
    int i = h >> 5, q = h & 31;
    wf[24576 + h] = W3[q * 128 + i];
  } else if (e < 53760) {               // W4T[q][p] = W4[p][q], f32
    int h = e - 53248;
    int q = h >> 4, p = h & 15;
    wf[28672 + h] = W4[p * 32 + q];
  }
}

// LDS arena (23552 B):
//   Y16 @ 0     : [64][104] bf16 (13312 B)  y staging, K-pad 96, +8 align pad
//   X16 @ 13312 : [64][40]  bf16 (5120 B)   X chunks (phase A) / a1 chunks (B2)
//   Zf  @ 18432 : [64][20]  f32  (5120 B)   z hand-off to CDE
__global__ __launch_bounds__(64) void mlp_mfma(
    const float* __restrict__ coords, const float* __restrict__ Bm,
    const float* __restrict__ b1, const float* __restrict__ L2,
    const float* __restrict__ b2, const float* __restrict__ b3v,
    const float* __restrict__ b4v, const float* __restrict__ W5,
    const float* __restrict__ b5, const void* __restrict__ ws,
    float* __restrict__ out) {
  const int l = threadIdx.x;
  const int lo = l & 15, hi = l >> 4;
  const int pix = blockIdx.x * 64 + l;
  const int bb = pix >> 12, hw = pix & 4095;
  const float c0 = coords[bb * 8192 + hw];
  const float c1 = coords[bb * 8192 + 4096 + hw];

  __shared__ __align__(16) char smem[23552];
  unsigned short* Y16 = (unsigned short*)smem;
  unsigned short* X16 = (unsigned short*)(smem + 13312);
  float* Zf = (float*)(smem + 18432);

  const unsigned short* R1p = (const unsigned short*)ws;
  const unsigned short* L1p = ((const unsigned short*)ws) + 20480;
  const unsigned short* R2p = ((const unsigned short*)ws) + 45056;
  const float* wf = (const float*)ws;
  const float* W3T = wf + 24576;
  const float* W4T = wf + 28672;

  const f32x4 fz = {0.0f, 0.0f, 0.0f, 0.0f};

  // ---- Phase A: y = X @ R1T, y frags [4 mt][5 nt]
  f32x4 y[4][5];
#pragma unroll
  for (int mt = 0; mt < 4; ++mt)
#pragma unroll
    for (int nt = 0; nt < 5; ++nt) y[mt][nt] = fz;

  for (int kt = 0; kt < 8; ++kt) {
    __syncthreads();                        // protect X16 reuse
    unsigned* Xw = (unsigned*)X16;
#pragma unroll
    for (int i = 0; i < 16; ++i) {
      int m = kt * 16 + i;
      float u = fmaf(c0, Bm[m], c1 * Bm[128 + m]);
      float t = u - floorf(u);              // v_sin/v_cos take revolutions
      float s = __builtin_amdgcn_sinf(t);
      float c = __builtin_amdgcn_cosf(t);
      Xw[l * 20 + i] = (unsigned)f2bf(s) | ((unsigned)f2bf(c) << 16);
    }
    __syncthreads();
    bf16x8 af[4], bfr[5];
#pragma unroll
    for (int mt = 0; mt < 4; ++mt)
      af[mt] = *(const bf16x8*)(X16 + (mt * 16 + lo) * 40 + hi * 8);
#pragma unroll
    for (int nt = 0; nt < 5; ++nt)
      bfr[nt] = *(const bf16x8*)(R1p + ((kt * 80 + nt * 16 + lo) * 4 + hi) * 8);
#pragma unroll
    for (int mt = 0; mt < 4; ++mt)
#pragma unroll
      for (int nt = 0; nt < 5; ++nt)
        y[mt][nt] = __builtin_amdgcn_mfma_f32_16x16x32_bf16(af[mt], bfr[nt],
                                                            y[mt][nt], 0, 0, 0);
  }

  // ---- y C-frags -> Y16 (bf16), zero-pad cols 80..95
#pragma unroll
  for (int mt = 0; mt < 4; ++mt)
#pragma unroll
    for (int nt = 0; nt < 5; ++nt)
#pragma unroll
      for (int r = 0; r < 4; ++r)
        Y16[(mt * 16 + hi * 4 + r) * 104 + nt * 16 + lo] = f2bf(y[mt][nt][r]);
  *(i32x4*)(Y16 + l * 104 + 80) = (i32x4){0, 0, 0, 0};
  *(i32x4*)(Y16 + l * 104 + 88) = (i32x4){0, 0, 0, 0};
  __syncthreads();

  // ---- Phase B1 + B2 interleaved
  bf16x8 ay[4][3];
#pragma unroll
  for (int mt = 0; mt < 4; ++mt)
#pragma unroll
    for (int kt = 0; kt < 3; ++kt)
      ay[mt][kt] = *(const bf16x8*)(Y16 + (mt * 16 + lo) * 104 + kt * 32 + hi * 8);

  f32x4 zfr[4];
#pragma unroll
  for (int mt = 0; mt < 4; ++mt) zfr[mt] = fz;

  for (int nt = 0; nt < 16; ++nt) {
    f32x4 cf[4];
#pragma unroll
    for (int mt = 0; mt < 4; ++mt) cf[mt] = fz;
#pragma unroll
    for (int kt = 0; kt < 3; ++kt) {
      bf16x8 bl = *(const bf16x8*)(L1p + ((kt * 256 + nt * 16 + lo) * 4 + hi) * 8);
#pragma unroll
      for (int mt = 0; mt < 4; ++mt)
        cf[mt] = __builtin_amdgcn_mfma_f32_16x16x32_bf16(ay[mt][kt], bl,
                                                         cf[mt], 0, 0, 0);
    }
    float bias = b1[nt * 16 + lo];          // C-frag col = nt*16+lo
#pragma unroll
    for (int mt = 0; mt < 4; ++mt)
#pragma unroll
      for (int r = 0; r < 4; ++r) {
        float v = fmaxf(cf[mt][r] + bias, 0.0f);
        X16[(mt * 16 + hi * 4 + r) * 40 + (nt & 1) * 16 + lo] = f2bf(v);
      }
    if (nt & 1) {                           // B2 round rd over 32 j's
      __syncthreads();
      int rd = nt >> 1;
      bf16x8 br = *(const bf16x8*)(R2p + ((rd * 16 + lo) * 4 + hi) * 8);
#pragma unroll
      for (int mt = 0; mt < 4; ++mt) {
        bf16x8 aa = *(const bf16x8*)(X16 + (mt * 16 + lo) * 40 + hi * 8);
        zfr[mt] = __builtin_amdgcn_mfma_f32_16x16x32_bf16(aa, br, zfr[mt],
                                                          0, 0, 0);
      }
      __syncthreads();                      // before next nt's staging writes
    }
  }

  // ---- z frags -> Zf, per-lane pickup
#pragma unroll
  for (int mt = 0; mt < 4; ++mt)
#pragma unroll
    for (int r = 0; r < 4; ++r)
      Zf[(mt * 16 + hi * 4 + r) * 20 + lo] = zfr[mt][r];
  __syncthreads();
  float zl[10];
#pragma unroll
  for (int t = 0; t < 10; ++t) zl[t] = Zf[l * 20 + t];

  // ---- Phase C: a2 = relu(z @ L2^T + b2) streamed into o3 = a2 @ W3^T + b3
  float o3[32];
#pragma unroll
  for (int q = 0; q < 32; ++q) o3[q] = b3v[q];
  for (int i = 0; i < 128; ++i) {
    float d = b2[i];
    const float* __restrict__ lw = L2 + i * 10;
#pragma unroll
    for (int t = 0; t < 10; ++t) d = fmaf(zl[t], lw[t], d);
    d = fmaxf(d, 0.0f);
    const float* __restrict__ w3 = W3T + i * 32;
#pragma unroll
    for (int q = 0; q < 32; ++q) o3[q] = fmaf(d, w3[q], o3[q]);
  }

  // ---- Phase D
  float o4[16];
#pragma unroll
  for (int p = 0; p < 16; ++p) o4[p] = b4v[p];
#pragma unroll
  for (int q = 0; q < 32; ++q) {
    float a = fmaxf(o3[q], 0.0f);
    const float* __restrict__ w4 = W4T + q * 16;
#pragma unroll
    for (int p = 0; p < 16; ++p) o4[p] = fmaf(a, w4[p], o4[p]);
  }
#pragma unroll
  for (int p = 0; p < 16; ++p) o4[p] = fmaxf(o4[p], 0.0f);

  // ---- Phase E
#pragma unroll
  for (int e = 0; e < 3; ++e) {
    float acc = b5[e];
    const float* __restrict__ w5 = W5 + e * 16;
#pragma unroll
    for (int p = 0; p < 16; ++p) acc = fmaf(o4[p], w5[p], acc);
    out[pix * 3 + e] = acc;
  }
}

extern "C" void kernel_launch(void* const* d_in, const int* in_sizes, int n_in,
                              void* d_out, int out_size, void* d_ws, size_t ws_size,
                              hipStream_t stream) {
  const float* coords = (const float*)d_in[0];
  const float* Bmat   = (const float*)d_in[1];
  const float* L1     = (const float*)d_in[2];
  const float* R1     = (const float*)d_in[3];
  const float* b1     = (const float*)d_in[4];
  const float* L2     = (const float*)d_in[5];
  const float* R2     = (const float*)d_in[6];
  const float* b2     = (const float*)d_in[7];
  const float* W3     = (const float*)d_in[8];
  const float* b3     = (const float*)d_in[9];
  const float* W4     = (const float*)d_in[10];
  const float* b4     = (const float*)d_in[11];
  const float* W5     = (const float*)d_in[12];
  const float* b5     = (const float*)d_in[13];

  prep_pack<<<210, 256, 0, stream>>>(R1, L1, R2, W3, W4, d_ws);
  mlp_mfma<<<8192, 64, 0, stream>>>(coords, Bmat, b1, L2, b2, b3, b4, W5, b5,
                                    d_ws, (float*)d_out);
}

// Round 3
// 168.207 us; speedup vs baseline: 3.8108x; 2.0354x over previous
//
#include <hip/hip_runtime.h>

// ImplicitMLP, all GEMM phases on MFMA (bf16 in / fp32 acc), per-lane fp32 D/E.
// 1 wave = 64 pixels/block. Phase A computes X A-frags directly in registers
// (no LDS staging). LDS arena 13312 B, regions reused across phases:
//   Y16 @0    [64][104] bf16  (A->B1 transform; dead after ay loads)
//   X16 @0    [64][40]  bf16  (B1->B2 and C1->C2 staging; aliases Y16)
//   Z16 @5632 [64][32]  bf16  (z staging, cols 16..31 zeroed)
//   O3f @0    [64][33]  f32   (o3 hand-off to per-lane D/E)
//
// ws (prep_pack output): bf16 @short-idx:
//   R1p 0      [kt8][n80][k32]   (k = interleaved sin/cos feature order)
//   L1p 20480  [kt3][n256][k32]  (k>=70 zero)
//   R2p 45056  [kt8][n16][k32]   (n>=10 zero)
//   L2p 49152  [nt8][n16][k32]   (k>=10 zero)
//   W3p 53248  [rd4][nt2_2][n16][k32]
// f32 @dword 28672: W4T [q32][p16]

typedef __attribute__((ext_vector_type(8))) short bf16x8;
typedef __attribute__((ext_vector_type(4))) float f32x4;
typedef __attribute__((ext_vector_type(4))) int i32x4;

__device__ inline unsigned short f2bf(float f) {       // RNE (weights, prep)
  unsigned u = __float_as_uint(f);
  return (unsigned short)((u + 0x7FFFu + ((u >> 16) & 1u)) >> 16);
}
__device__ inline unsigned short f2bf_fast(float f) {  // round-half-up (acts)
  return (unsigned short)((__float_as_uint(f) + 0x8000u) >> 16);
}
__device__ inline unsigned packbf(float s, float c) {  // low=sin, high=cos
  return (unsigned)((__float_as_uint(s) + 0x8000u) >> 16) |
         ((__float_as_uint(c) + 0x8000u) & 0xFFFF0000u);
}

__global__ __launch_bounds__(256) void prep_pack(
    const float* __restrict__ R1, const float* __restrict__ L1,
    const float* __restrict__ R2, const float* __restrict__ L2,
    const float* __restrict__ W3, const float* __restrict__ W4,
    void* __restrict__ ws) {
  unsigned short* w16 = (unsigned short*)ws;
  float* wf = (float*)ws;
  int e = blockIdx.x * 256 + threadIdx.x;
  if (e < 20480) {                       // R1p: B[k=feat][n=r]
    int kt = e / 2560, rem = e % 2560;
    int n = rem >> 5, oj = rem & 31;
    int k = kt * 32 + oj;
    int feat = (k & 1) ? 128 + (k >> 1) : (k >> 1);
    w16[e] = f2bf((n < 70) ? R1[n * 256 + feat] : 0.0f);
  } else if (e < 45056) {                // L1p: B[k=r][n=j]
    int f = e - 20480;
    int kt = f / 8192, rem = f % 8192;
    int n = rem >> 5, oj = rem & 31;
    int k = kt * 32 + oj;
    w16[e] = f2bf((k < 70) ? L1[n * 70 + k] : 0.0f);
  } else if (e < 49152) {                // R2p: B[k=j][n=t]
    int f = e - 45056;
    int kt = f / 512, rem = f % 512;
    int n = rem >> 5, k = kt * 32 + (rem & 31);
    w16[e] = f2bf((n < 10) ? R2[n * 256 + k] : 0.0f);
  } else if (e < 53248) {                // L2p: B[k=t][n=i]
    int f = e - 49152;
    int j = f & 7, h = (f >> 3) & 3, n = (f >> 5) & 15, nt = f >> 9;
    int k = h * 8 + j;
    w16[e] = f2bf((k < 10) ? L2[(nt * 16 + n) * 10 + k] : 0.0f);
  } else if (e < 57344) {                // W3p: B[k=i][n=q]
    int f = e - 53248;
    int j = f & 7, h = (f >> 3) & 3, n = (f >> 5) & 15;
    int nt2 = (f >> 9) & 1, rd = f >> 10;
    w16[e] = f2bf(W3[(nt2 * 16 + n) * 128 + rd * 32 + h * 8 + j]);
  } else if (e < 57856) {                // W4T[q][p] = W4[p][q], f32
    int h2 = e - 57344;
    int q = h2 >> 4, p = h2 & 15;
    wf[28672 + h2] = W4[p * 32 + q];
  }
}

__global__ __launch_bounds__(64, 2) void mlp_mfma(
    const float* __restrict__ coords, const float* __restrict__ Bm,
    const float* __restrict__ b1, const float* __restrict__ b2,
    const float* __restrict__ b3v, const float* __restrict__ b4v,
    const float* __restrict__ W5, const float* __restrict__ b5,
    const void* __restrict__ ws, float* __restrict__ out) {
  const int l = threadIdx.x;
  const int lo = l & 15, hi = l >> 4;
  const int pix0 = blockIdx.x * 64;

  __shared__ __align__(16) char smem[13312];
  unsigned short* Y16 = (unsigned short*)smem;           // [64][104]
  unsigned short* X16 = (unsigned short*)smem;           // [64][40] (alias)
  unsigned short* Z16 = (unsigned short*)(smem + 5632);  // [64][32]
  float* O3f = (float*)smem;                             // [64][33] (alias)

  const unsigned short* R1p = (const unsigned short*)ws;
  const unsigned short* L1p = ((const unsigned short*)ws) + 20480;
  const unsigned short* R2p = ((const unsigned short*)ws) + 45056;
  const unsigned short* L2p = ((const unsigned short*)ws) + 49152;
  const unsigned short* W3p = ((const unsigned short*)ws) + 53248;
  const float* W4T = ((const float*)ws) + 28672;

  const f32x4 fz = {0.0f, 0.0f, 0.0f, 0.0f};

  // coords for the 4 pixels this lane covers as MFMA A-operand rows
  float c0m[4], c1m[4];
#pragma unroll
  for (int mt = 0; mt < 4; ++mt) {
    int p = pix0 + mt * 16 + lo;
    int bb = p >> 12, hw = p & 4095;
    c0m[mt] = coords[bb * 8192 + hw];
    c1m[mt] = coords[bb * 8192 + 4096 + hw];
  }

  // ---- Phase A: y = X @ R1T. A-frags built in registers.
  f32x4 y[4][5];
#pragma unroll
  for (int mt = 0; mt < 4; ++mt)
#pragma unroll
    for (int nt = 0; nt < 5; ++nt) y[mt][nt] = fz;

  float bm0[4], bm1[4];
#pragma unroll
  for (int p = 0; p < 4; ++p) {
    int m = hi * 4 + p;
    bm0[p] = Bm[m]; bm1[p] = Bm[128 + m];
  }
  for (int kt = 0; kt < 8; ++kt) {
    float nb0[4], nb1[4];
    if (kt < 7) {
#pragma unroll
      for (int p = 0; p < 4; ++p) {
        int m = (kt + 1) * 16 + hi * 4 + p;
        nb0[p] = Bm[m]; nb1[p] = Bm[128 + m];
      }
    }
    bf16x8 bfr[5];
#pragma unroll
    for (int nt = 0; nt < 5; ++nt)
      bfr[nt] = *(const bf16x8*)(R1p + ((kt * 80 + nt * 16 + lo) * 4 + hi) * 8);
    bf16x8 af[4];
#pragma unroll
    for (int mt = 0; mt < 4; ++mt) {
#pragma unroll
      for (int p = 0; p < 4; ++p) {
        float u = fmaf(c0m[mt], bm0[p], c1m[mt] * bm1[p]);
        float t = u - floorf(u);               // v_sin/v_cos in revolutions
        float s = __builtin_amdgcn_sinf(t);
        float c = __builtin_amdgcn_cosf(t);
        ((unsigned*)&af[mt])[p] = packbf(s, c);
      }
    }
#pragma unroll
    for (int mt = 0; mt < 4; ++mt)
#pragma unroll
      for (int nt = 0; nt < 5; ++nt)
        y[mt][nt] = __builtin_amdgcn_mfma_f32_16x16x32_bf16(af[mt], bfr[nt],
                                                            y[mt][nt], 0, 0, 0);
#pragma unroll
    for (int p = 0; p < 4; ++p) { bm0[p] = nb0[p]; bm1[p] = nb1[p]; }
  }

  // ---- y C-frags -> Y16 bf16, zero-pad cols 80..95
#pragma unroll
  for (int mt = 0; mt < 4; ++mt)
#pragma unroll
    for (int nt = 0; nt < 5; ++nt)
#pragma unroll
      for (int r = 0; r < 4; ++r)
        Y16[(mt * 16 + hi * 4 + r) * 104 + nt * 16 + lo] = f2bf_fast(y[mt][nt][r]);
  *(i32x4*)(Y16 + l * 104 + 80) = (i32x4){0, 0, 0, 0};
  *(i32x4*)(Y16 + l * 104 + 88) = (i32x4){0, 0, 0, 0};
  __syncthreads();

  bf16x8 ay[4][3];
#pragma unroll
  for (int mt = 0; mt < 4; ++mt)
#pragma unroll
    for (int kt = 0; kt < 3; ++kt)
      ay[mt][kt] = *(const bf16x8*)(Y16 + (mt * 16 + lo) * 104 + kt * 32 + hi * 8);
  __syncthreads();   // Y16 dead; X16 (aliased) may now be written

  // ---- B1 (a1 = relu(y@L1T+b1)) interleaved with B2 (z += a1@R2T)
  f32x4 zfr[4];
#pragma unroll
  for (int mt = 0; mt < 4; ++mt) zfr[mt] = fz;

  bf16x8 blc[3];
#pragma unroll
  for (int kt = 0; kt < 3; ++kt)
    blc[kt] = *(const bf16x8*)(L1p + ((kt * 256 + lo) * 4 + hi) * 8);

#pragma unroll 2
  for (int nt = 0; nt < 16; ++nt) {
    bf16x8 bln[3];
    if (nt < 15) {
#pragma unroll
      for (int kt = 0; kt < 3; ++kt)
        bln[kt] = *(const bf16x8*)(L1p + ((kt * 256 + (nt + 1) * 16 + lo) * 4 + hi) * 8);
    }
    float bias = b1[nt * 16 + lo];
    f32x4 cf[4];
#pragma unroll
    for (int mt = 0; mt < 4; ++mt) cf[mt] = fz;
#pragma unroll
    for (int kt = 0; kt < 3; ++kt)
#pragma unroll
      for (int mt = 0; mt < 4; ++mt)
        cf[mt] = __builtin_amdgcn_mfma_f32_16x16x32_bf16(ay[mt][kt], blc[kt],
                                                         cf[mt], 0, 0, 0);
#pragma unroll
    for (int mt = 0; mt < 4; ++mt)
#pragma unroll
      for (int r = 0; r < 4; ++r)
        X16[(mt * 16 + hi * 4 + r) * 40 + (nt & 1) * 16 + lo] =
            f2bf_fast(fmaxf(cf[mt][r] + bias, 0.0f));
    if (nt & 1) {
      __syncthreads();
      int rd = nt >> 1;
      bf16x8 br = *(const bf16x8*)(R2p + ((rd * 16 + lo) * 4 + hi) * 8);
#pragma unroll
      for (int mt = 0; mt < 4; ++mt) {
        bf16x8 aa = *(const bf16x8*)(X16 + (mt * 16 + lo) * 40 + hi * 8);
        zfr[mt] = __builtin_amdgcn_mfma_f32_16x16x32_bf16(aa, br, zfr[mt],
                                                          0, 0, 0);
      }
      __syncthreads();
    }
#pragma unroll
    for (int kt = 0; kt < 3; ++kt) blc[kt] = bln[kt];
  }

  // ---- z frags -> Z16 bf16 (cols 16..31 zeroed), reload as A-frags
#pragma unroll
  for (int mt = 0; mt < 4; ++mt)
#pragma unroll
    for (int r = 0; r < 4; ++r)
      Z16[(mt * 16 + hi * 4 + r) * 32 + lo] = f2bf_fast(zfr[mt][r]);
  *(i32x4*)(Z16 + l * 32 + 16) = (i32x4){0, 0, 0, 0};
  *(i32x4*)(Z16 + l * 32 + 24) = (i32x4){0, 0, 0, 0};
  __syncthreads();
  bf16x8 az[4];
#pragma unroll
  for (int mt = 0; mt < 4; ++mt)
    az[mt] = *(const bf16x8*)(Z16 + (mt * 16 + lo) * 32 + hi * 8);
  __syncthreads();

  // ---- C1 (a2 = relu(z@L2T+b2)) interleaved with C2 (o3 += a2@W3T)
  f32x4 o3fr[4][2];
#pragma unroll
  for (int mt = 0; mt < 4; ++mt) { o3fr[mt][0] = fz; o3fr[mt][1] = fz; }

  bf16x8 wlc = *(const bf16x8*)(L2p + (lo * 4 + hi) * 8);
#pragma unroll 2
  for (int nt = 0; nt < 8; ++nt) {
    bf16x8 wln;
    if (nt < 7)
      wln = *(const bf16x8*)(L2p + (((nt + 1) * 16 + lo) * 4 + hi) * 8);
    float bias = b2[nt * 16 + lo];
    f32x4 cf[4];
#pragma unroll
    for (int mt = 0; mt < 4; ++mt)
      cf[mt] = __builtin_amdgcn_mfma_f32_16x16x32_bf16(az[mt], wlc, fz, 0, 0, 0);
#pragma unroll
    for (int mt = 0; mt < 4; ++mt)
#pragma unroll
      for (int r = 0; r < 4; ++r)
        X16[(mt * 16 + hi * 4 + r) * 40 + (nt & 1) * 16 + lo] =
            f2bf_fast(fmaxf(cf[mt][r] + bias, 0.0f));
    if (nt & 1) {
      __syncthreads();
      int rd = nt >> 1;
      bf16x8 aa[4];
#pragma unroll
      for (int mt = 0; mt < 4; ++mt)
        aa[mt] = *(const bf16x8*)(X16 + (mt * 16 + lo) * 40 + hi * 8);
#pragma unroll
      for (int nt2 = 0; nt2 < 2; ++nt2) {
        bf16x8 bw = *(const bf16x8*)(W3p + (((rd * 2 + nt2) * 16 + lo) * 4 + hi) * 8);
#pragma unroll
        for (int mt = 0; mt < 4; ++mt)
          o3fr[mt][nt2] = __builtin_amdgcn_mfma_f32_16x16x32_bf16(
              aa[mt], bw, o3fr[mt][nt2], 0, 0, 0);
      }
      __syncthreads();
    }
    wlc = wln;
  }

  // ---- o3 (+b3, relu) -> O3f f32 hand-off
#pragma unroll
  for (int mt = 0; mt < 4; ++mt)
#pragma unroll
    for (int nt2 = 0; nt2 < 2; ++nt2)
#pragma unroll
      for (int r = 0; r < 4; ++r)
        O3f[(mt * 16 + hi * 4 + r) * 33 + nt2 * 16 + lo] =
            fmaxf(o3fr[mt][nt2][r] + b3v[nt2 * 16 + lo], 0.0f);
  __syncthreads();

  // ---- Per-lane fp32 D/E (weights via uniform s_load)
  float o3l[32];
#pragma unroll
  for (int q = 0; q < 32; ++q) o3l[q] = O3f[l * 33 + q];

  float o4[16];
#pragma unroll
  for (int p = 0; p < 16; ++p) o4[p] = b4v[p];
#pragma unroll
  for (int q = 0; q < 32; ++q) {
    float a = o3l[q];                       // already relu'd
    const float* __restrict__ w4 = W4T + q * 16;
#pragma unroll
    for (int p = 0; p < 16; ++p) o4[p] = fmaf(a, w4[p], o4[p]);
  }
#pragma unroll
  for (int p = 0; p < 16; ++p) o4[p] = fmaxf(o4[p], 0.0f);

#pragma unroll
  for (int e = 0; e < 3; ++e) {
    float acc = b5[e];
    const float* __restrict__ w5 = W5 + e * 16;
#pragma unroll
    for (int p = 0; p < 16; ++p) acc = fmaf(o4[p], w5[p], acc);
    out[(pix0 + l) * 3 + e] = acc;
  }
}

extern "C" void kernel_launch(void* const* d_in, const int* in_sizes, int n_in,
                              void* d_out, int out_size, void* d_ws, size_t ws_size,
                              hipStream_t stream) {
  const float* coords = (const float*)d_in[0];
  const float* Bmat   = (const float*)d_in[1];
  const float* L1     = (const float*)d_in[2];
  const float* R1     = (const float*)d_in[3];
  const float* b1     = (const float*)d_in[4];
  const float* L2     = (const float*)d_in[5];
  const float* R2     = (const float*)d_in[6];
  const float* b2     = (const float*)d_in[7];
  const float* W3     = (const float*)d_in[8];
  const float* b3     = (const float*)d_in[9];
  const float* W4     = (const float*)d_in[10];
  const float* b4     = (const float*)d_in[11];
  const float* W5     = (const float*)d_in[12];
  const float* b5     = (const float*)d_in[13];

  prep_pack<<<227, 256, 0, stream>>>(R1, L1, R2, L2, W3, W4, d_ws);
  mlp_mfma<<<8192, 64, 0, stream>>>(coords, Bmat, b1, b2, b3, b4, W5, b5,
                                    d_ws, (float*)d_out);
}